// Round 2
// baseline (4874.454 us; speedup 1.0000x reference)
//
#include <hip/hip_runtime.h>
#include <stdint.h>

#define GAS __attribute__((address_space(1)))
#define LAS __attribute__((address_space(3)))

typedef __bf16 v8bf __attribute__((ext_vector_type(8)));
typedef float v4f __attribute__((ext_vector_type(4)));
typedef unsigned short u16;

constexpr int kB = 256, kT = 128, kI = 512, kH = 1024, kO = 32;
constexpr int kBlocks = 256, kThreads = 256;
constexpr int BK = 64;
constexpr int NCX = kI / BK;   // 8 x-chunks
constexpr int NCH = kH / BK;   // 16 h-chunks

// workspace layout (bytes)
constexpr size_t OFF_CNT = 0;                                  // barrier counter
constexpr size_t OFF_H   = 1024;                               // 2 x [B][H] bf16 ping-pong
constexpr size_t OFF_X   = OFF_H + (size_t)2 * kB * kH * 2;    // x as bf16 [B][T][I]
constexpr size_t SZ_X    = (size_t)kB * kT * kI * 2;
constexpr size_t OFF_WI  = OFF_X + SZ_X;                       // 4 x [H][I] bf16
constexpr size_t SZ_WI   = (size_t)kH * kI * 2;
constexpr size_t OFF_WH  = OFF_WI + 4 * SZ_WI;                 // 4 x [H][H] bf16
constexpr size_t SZ_WH   = (size_t)kH * kH * 2;

struct LstmParams {
  const u16* x;         // bf16 (converted) [B][T][I]
  const u16* wi[4];     // bf16 gate order: i, f, g(candidate), o  [H][I]
  const u16* wh[4];     // bf16 [H][H]
  const float* bi[4];   // fp32 [H]
  const float* bh[4];   // fp32 [H]
  const float* wfc;     // fp32 [O][H]
  float* out;           // fp32 [B][O]
  unsigned* cnt;        // grid barrier counter
  u16* hbuf;            // 2 x [B][H] bf16 ping-pong
};

static __device__ __forceinline__ float b2f(u16 v) {
  union { float f; uint32_t i; } u; u.i = ((uint32_t)v) << 16; return u.f;
}
static __device__ __forceinline__ u16 f2b(float f) {
  union { float f; uint32_t i; } u; u.f = f;
  return (u16)((u.i + 0x7fffu + ((u.i >> 16) & 1u)) >> 16);
}
static __device__ __forceinline__ float sigm(float x) { return 1.f / (1.f + __expf(-x)); }
static __device__ __forceinline__ float tanh_f(float x) {
  float e = __expf(2.f * x);
  return 1.f - 2.f / (e + 1.f);
}
// plain async global->LDS, 16B/lane (LDS dest = wave-uniform base + lane*16)
static __device__ __forceinline__ void ld16(const void* g, void* l) {
  __builtin_amdgcn_global_load_lds((const GAS uint32_t*)g, (LAS uint32_t*)l, 16, 0, 0);
}
// coherent (sc0|sc1): bypass L1/L2, read LLC — used for h so no acquire-inv needed
static __device__ __forceinline__ void ld16c(const void* g, void* l) {
  __builtin_amdgcn_global_load_lds((const GAS uint32_t*)g, (LAS uint32_t*)l, 16, 0, 0x11);
}

// fp32 -> bf16 conversion (grid-stride, 8 elems/thread-iter)
__global__ __launch_bounds__(256) void cvt_kernel(const float* __restrict__ s,
                                                  u16* __restrict__ d, int n8) {
  for (int i = blockIdx.x * blockDim.x + threadIdx.x; i < n8;
       i += gridDim.x * blockDim.x) {
    const float4* sp = (const float4*)(s + (size_t)i * 8);
    float4 a = sp[0], b = sp[1];
    uint32_t w0 = f2b(a.x) | ((uint32_t)f2b(a.y) << 16);
    uint32_t w1 = f2b(a.z) | ((uint32_t)f2b(a.w) << 16);
    uint32_t w2 = f2b(b.x) | ((uint32_t)f2b(b.y) << 16);
    uint32_t w3 = f2b(b.z) | ((uint32_t)f2b(b.w) << 16);
    uint4 o = {w0, w1, w2, w3};
    *(uint4*)(d + (size_t)i * 8) = o;
  }
}

__global__ __launch_bounds__(kThreads) void lstm_kernel(LstmParams p) {
  // A: 64 batch rows x BK k ; B: 4 gates x 16 units x BK k. XOR-swizzled 16B blobs.
  __shared__ u16 Ald[2][64 * BK];   // 16 KB
  __shared__ u16 Bld[2][64 * BK];   // 16 KB

  const int tid = threadIdx.x;
  const int lane = tid & 63;
  const int wv = tid >> 6;          // wave 0..3: owns batch rows [16wv,16wv+16), stages gate wv
  const int blk = blockIdx.x;
  const int mt = blk >> 6;          // batch tile 0..3  (64 rows)
  const int ut = blk & 63;          // unit tile 0..63  (16 hidden units)

  const int mloc = lane & 15;       // MFMA row (A) / unit col (B) / out col
  const int q = lane >> 4;          // MFMA quad
  const int uglob = ut * 16 + mloc; // this lane's hidden unit

  float bias[4];
#pragma unroll
  for (int g = 0; g < 4; ++g)
    bias[g] = p.bi[g][uglob] + p.bh[g][uglob];

  float creg[4] = {0.f, 0.f, 0.f, 0.f};  // cell state, register-resident all 128 steps

  const int srl = lane >> 3;  // staging: row within 8-row group
  const int ss = lane & 7;    // staging: 16B slot within row

  for (int t = 0; t < kT; ++t) {
    v4f acc[4];
#pragma unroll
    for (int g = 0; g < 4; ++g) acc[g] = (v4f){0.f, 0.f, 0.f, 0.f};

    const u16* hread = p.hbuf + (size_t)(t & 1) * kB * kH;
    u16* hwrite = p.hbuf + (size_t)((t + 1) & 1) * kB * kH;
    const int nch = (t == 0) ? NCX : (NCX + NCH);   // t=0: h==0, skip h chunks

    auto stage = [&](int c, int bufi) {
#pragma unroll
      for (int half = 0; half < 2; ++half) {
        const int base = wv * 16 + half * 8;
        const int r = base + srl;
        const int j = ss ^ (r & 7);  // XOR blob swizzle (2-way bank alias on read = free)
        // A rows (x for c<NCX, h otherwise)
        if (c < NCX) {
          const void* g = p.x + ((size_t)(mt * 64 + r) * kT + t) * kI + c * BK + j * 8;
          ld16(g, &Ald[bufi][base * BK]);
        } else {
          const void* g = hread + (size_t)(mt * 64 + r) * kH + (c - NCX) * BK + j * 8;
          ld16c(g, &Ald[bufi][base * BK]);
        }
        // B rows: gate wv, unit (r&15)
        const int u = ut * 16 + (r & 15);
        if (c < NCX) {
          ld16(p.wi[wv] + (size_t)u * kI + c * BK + j * 8, &Bld[bufi][base * BK]);
        } else {
          ld16(p.wh[wv] + (size_t)u * kH + (c - NCX) * BK + j * 8, &Bld[bufi][base * BK]);
        }
      }
    };

    stage(0, 0);
    int buf = 0;
    for (int c = 0; c < nch; ++c) {
      __syncthreads();                       // chunk c staged (vmcnt drained), buf^1 free
      if (c + 1 < nch) stage(c + 1, buf ^ 1);
#pragma unroll
      for (int c2 = 0; c2 < 2; ++c2) {
        const int ja = (c2 * 4 + q) ^ (mloc & 7);
        const v8bf av = *(const v8bf*)&Ald[buf][(wv * 16 + mloc) * BK + ja * 8];
#pragma unroll
        for (int g = 0; g < 4; ++g) {
          const v8bf bv = *(const v8bf*)&Bld[buf][(g * 16 + mloc) * BK + ja * 8];
          acc[g] = __builtin_amdgcn_mfma_f32_16x16x32_bf16(av, bv, acc[g], 0, 0, 0);
        }
      }
      buf ^= 1;
    }

    // gate update; C/D layout: col = lane&15 (unit), row = q*4 + reg (batch)
#pragma unroll
    for (int r = 0; r < 4; ++r) {
      const float iv = sigm(acc[0][r] + bias[0]);
      const float fv = sigm(acc[1][r] + bias[1]);
      const float gv = tanh_f(acc[2][r] + bias[2]);
      const float ov = sigm(acc[3][r] + bias[3]);
      creg[r] = fv * creg[r] + iv * gv;
      const float hv = ov * tanh_f(creg[r]);
      const int m = mt * 64 + wv * 16 + q * 4 + r;
      hwrite[(size_t)m * kH + uglob] = f2b(hv);
    }

    // grid barrier: release (threadfence -> wbL2 flushes h to LLC), relaxed spin.
    // No acquire-inv: h reads are sc0|sc1 coherent, weights stay L2-resident.
    __syncthreads();
    if (tid == 0) {
      __threadfence();
      __hip_atomic_fetch_add(p.cnt, 1u, __ATOMIC_RELEASE, __HIP_MEMORY_SCOPE_AGENT);
      const unsigned tgt = (unsigned)(t + 1) * kBlocks;
      while (__hip_atomic_load(p.cnt, __ATOMIC_RELAXED, __HIP_MEMORY_SCOPE_AGENT) < tgt)
        __builtin_amdgcn_s_sleep(1);
    }
    __syncthreads();
  }

  // FC + log_softmax: blocks 0..31, 8 batch rows x 32 cols each. h_last in hbuf[0].
  // Stage h rows through coherent global_load_lds (no stale-L2 hazard), then LDS reads.
  if (blk < 32) {
    u16* sh = &Ald[0][0];   // 16 KB: 8 rows x 1024 bf16
    const char* hbase = (const char*)(p.hbuf + (size_t)blk * 8 * kH);  // (128&1)==0 -> buf 0
#pragma unroll
    for (int cc = 0; cc < 4; ++cc) {
      const char* g = hbase + cc * 4096 + wv * 1024 + lane * 16;
      ld16c(g, (char*)sh + cc * 4096 + wv * 1024);
    }
    __syncthreads();
    const int row = tid >> 5;   // 0..7 local row
    const int col = tid & 31;
    const u16* hr = sh + row * kH;
    const float* wr = p.wfc + (size_t)col * kH;
    float s = 0.f;
    for (int k = 0; k < kH; k += 4) {
      const float4 w4 = *(const float4*)(wr + k);
      s += b2f(hr[k]) * w4.x + b2f(hr[k + 1]) * w4.y +
           b2f(hr[k + 2]) * w4.z + b2f(hr[k + 3]) * w4.w;
    }
    float mx = s;
#pragma unroll
    for (int off = 16; off; off >>= 1) mx = fmaxf(mx, __shfl_xor(mx, off, 32));
    const float ex = __expf(s - mx);
    float se = ex;
#pragma unroll
    for (int off = 16; off; off >>= 1) se += __shfl_xor(se, off, 32);
    p.out[(blk * 8 + row) * kO + col] = s - mx - __logf(se);
  }
}

extern "C" void kernel_launch(void* const* d_in, const int* in_sizes, int n_in,
                              void* d_out, int out_size, void* d_ws, size_t ws_size,
                              hipStream_t stream) {
  (void)in_sizes; (void)n_in; (void)out_size; (void)ws_size;
  char* ws = (char*)d_ws;

  // bf16 copies in workspace
  u16* xb = (u16*)(ws + OFF_X);
  u16* wib[4], *whb[4];
  for (int g = 0; g < 4; ++g) {
    wib[g] = (u16*)(ws + OFF_WI + (size_t)g * SZ_WI);
    whb[g] = (u16*)(ws + OFF_WH + (size_t)g * SZ_WH);
  }

  // input dict order: x, (w_ii,w_hi,b_ii,b_hi), (w_if,w_hf,b_if,b_hf),
  //                   (w_io,w_ho,b_io,b_ho), (w_ic,w_hc,b_ic,b_hc), w_fc
  // struct gate order: 0=i, 1=f, 2=g(candidate), 3=o
  const float* xf = (const float*)d_in[0];
  const int gsrc[4] = {1, 5, 13, 9};  // base input index for gates i, f, g, o

  hipMemsetAsync(d_ws, 0, 1024, stream);  // zero barrier counter (ws is 0xAA-poisoned)

  // fp32 -> bf16 conversions
  cvt_kernel<<<2048, 256, 0, stream>>>(xf, xb, kB * kT * kI / 8);
  for (int g = 0; g < 4; ++g) {
    cvt_kernel<<<512, 256, 0, stream>>>((const float*)d_in[gsrc[g]], wib[g], kH * kI / 8);
    cvt_kernel<<<1024, 256, 0, stream>>>((const float*)d_in[gsrc[g] + 1], whb[g], kH * kH / 8);
  }

  LstmParams p;
  p.x = xb;
  for (int g = 0; g < 4; ++g) {
    p.wi[g] = wib[g];
    p.wh[g] = whb[g];
    p.bi[g] = (const float*)d_in[gsrc[g] + 2];
    p.bh[g] = (const float*)d_in[gsrc[g] + 3];
  }
  p.wfc = (const float*)d_in[17];
  p.out = (float*)d_out;
  p.cnt = (unsigned*)(ws + OFF_CNT);
  p.hbuf = (u16*)(ws + OFF_H);

  void* args[] = {&p};
  hipLaunchCooperativeKernel((void*)lstm_kernel, dim3(kBlocks), dim3(kThreads),
                             args, 0, stream);
}

// Round 3
// 2888.759 us; speedup vs baseline: 1.6874x; 1.6874x over previous
//
#include <hip/hip_runtime.h>
#include <stdint.h>

#define GAS __attribute__((address_space(1)))
#define LAS __attribute__((address_space(3)))

typedef __bf16 v8bf __attribute__((ext_vector_type(8)));
typedef float v4f __attribute__((ext_vector_type(4)));
typedef unsigned short u16;

constexpr int kB = 256, kT = 128, kI = 512, kH = 1024, kO = 32;
constexpr int kBlocks = 256, kThreads = 256;
constexpr int BK = 128;
constexpr int NCX = kI / BK;   // 4 x-chunks
constexpr int NCH = kH / BK;   // 8 h-chunks
constexpr int NBLOB = BK * 2 / 16;  // 16 16B-blobs per row

// workspace layout (bytes)
constexpr size_t OFF_FLG = 0;                                  // flags[4][64] barrier slots
constexpr size_t OFF_H   = 1024;                               // 2 x [B][H] bf16 ping-pong
constexpr size_t OFF_X   = OFF_H + (size_t)2 * kB * kH * 2;    // x as bf16 [B][T][I]
constexpr size_t SZ_X    = (size_t)kB * kT * kI * 2;
constexpr size_t OFF_WI  = OFF_X + SZ_X;                       // 4 x [H][I] bf16
constexpr size_t SZ_WI   = (size_t)kH * kI * 2;
constexpr size_t OFF_WH  = OFF_WI + 4 * SZ_WI;                 // 4 x [H][H] bf16
constexpr size_t SZ_WH   = (size_t)kH * kH * 2;

struct LstmParams {
  const u16* x;         // bf16 (converted) [B][T][I]
  const u16* wi[4];     // bf16 gate order: i, f, g(candidate), o  [H][I]
  const u16* wh[4];     // bf16 [H][H]
  const float* bi[4];   // fp32 [H]
  const float* bh[4];   // fp32 [H]
  const float* wfc;     // fp32 [O][H]
  float* out;           // fp32 [B][O]
  unsigned* flags;      // [4][64] per-group arrival flags
  u16* hbuf;            // 2 x [B][H] bf16 ping-pong
};

static __device__ __forceinline__ float b2f(u16 v) {
  union { float f; uint32_t i; } u; u.i = ((uint32_t)v) << 16; return u.f;
}
static __device__ __forceinline__ u16 f2b(float f) {
  union { float f; uint32_t i; } u; u.f = f;
  return (u16)((u.i + 0x7fffu + ((u.i >> 16) & 1u)) >> 16);
}
static __device__ __forceinline__ float sigm(float x) { return 1.f / (1.f + __expf(-x)); }
static __device__ __forceinline__ float tanh_f(float x) {
  float e = __expf(2.f * x);
  return 1.f - 2.f / (e + 1.f);
}
// plain async global->LDS, 16B/lane (LDS dest = wave-uniform base + lane*16)
static __device__ __forceinline__ void ld16(const void* g, void* l) {
  __builtin_amdgcn_global_load_lds((const GAS uint32_t*)g, (LAS uint32_t*)l, 16, 0, 0);
}
// coherent (sc0|sc1): bypass L1/L2, read LLC — used for h so no acquire-inv needed
static __device__ __forceinline__ void ld16c(const void* g, void* l) {
  __builtin_amdgcn_global_load_lds((const GAS uint32_t*)g, (LAS uint32_t*)l, 16, 0, 0x11);
}

// fp32 -> bf16 conversion (grid-stride, 8 elems/thread-iter)
__global__ __launch_bounds__(256) void cvt_kernel(const float* __restrict__ s,
                                                  u16* __restrict__ d, int n8) {
  for (int i = blockIdx.x * blockDim.x + threadIdx.x; i < n8;
       i += gridDim.x * blockDim.x) {
    const float4* sp = (const float4*)(s + (size_t)i * 8);
    float4 a = sp[0], b = sp[1];
    uint32_t w0 = f2b(a.x) | ((uint32_t)f2b(a.y) << 16);
    uint32_t w1 = f2b(a.z) | ((uint32_t)f2b(a.w) << 16);
    uint32_t w2 = f2b(b.x) | ((uint32_t)f2b(b.y) << 16);
    uint32_t w3 = f2b(b.z) | ((uint32_t)f2b(b.w) << 16);
    uint4 o = {w0, w1, w2, w3};
    *(uint4*)(d + (size_t)i * 8) = o;
  }
}

__global__ __launch_bounds__(kThreads) void lstm_kernel(LstmParams p) {
  // A: 64 batch rows x BK k ; B: 4 gates x 16 units x BK k. XOR-16 blob swizzle.
  __shared__ u16 Ald[2][64 * BK];   // 32 KB
  __shared__ u16 Bld[2][64 * BK];   // 32 KB

  const int tid = threadIdx.x;
  const int lane = tid & 63;
  const int wv = tid >> 6;          // wave 0..3: owns batch rows [16wv,16wv+16), stages gate wv
  const int blk = blockIdx.x;
  // XCD-aware swizzle: the 4 blocks sharing a ut land on one XCD (round-robin %8)
  const int mt = (blk >> 3) & 3;            // batch tile 0..3 (64 rows) = barrier group
  const int ut = (blk & 7) * 8 + (blk >> 5);// unit tile 0..63 (16 hidden units)

  const int mloc = lane & 15;       // MFMA row (A) / unit col (B) / out col
  const int q = lane >> 4;          // MFMA quad
  const int uglob = ut * 16 + mloc; // this lane's hidden unit

  unsigned* gflags = p.flags + mt * 64;   // this group's 64 arrival slots

  float bias[4];
#pragma unroll
  for (int g = 0; g < 4; ++g)
    bias[g] = p.bi[g][uglob] + p.bh[g][uglob];

  float creg[4] = {0.f, 0.f, 0.f, 0.f};  // cell state, register-resident all 128 steps

  // staging: round rr covers rows [wv*16+rr*4, +4); lane -> (row rl, slot lane&15)
  auto stage = [&](int t_, int c, int bufi) {
    const u16* hread = p.hbuf + (size_t)(t_ & 1) * kB * kH;
#pragma unroll
    for (int rr = 0; rr < 4; ++rr) {
      const int rl = rr * 4 + (lane >> 4);     // 0..15 row within wave's 16
      const int gb = (lane & 15) ^ rl;         // swizzled global blob index
      u16* Adst = &Ald[bufi][(wv * 16 + rr * 4) * BK];
      u16* Bdst = &Bld[bufi][(wv * 16 + rr * 4) * BK];
      const int m = mt * 64 + wv * 16 + rl;    // global batch row
      const int u = ut * 16 + rl;              // global hidden unit (gate wv)
      if (c < NCX) {
        ld16(p.x + ((size_t)m * kT + t_) * kI + c * BK + gb * 8, Adst);
        ld16(p.wi[wv] + (size_t)u * kI + c * BK + gb * 8, Bdst);
      } else {
        ld16c(hread + (size_t)m * kH + (c - NCX) * BK + gb * 8, Adst);
        ld16(p.wh[wv] + (size_t)u * kH + (c - NCX) * BK + gb * 8, Bdst);
      }
    }
  };

  for (int t = 0; t < kT; ++t) {
    v4f acc[4];
#pragma unroll
    for (int g = 0; g < 4; ++g) acc[g] = (v4f){0.f, 0.f, 0.f, 0.f};

    if (t == 0) {
      stage(0, 0, 0); stage(0, 1, 1);          // first-step x prefetch
    } else if (wv == 0) {
      // group barrier wait: 64 lanes read 64 flags in one coalesced load
      while (true) {
        unsigned v = __hip_atomic_load(&gflags[lane], __ATOMIC_RELAXED,
                                       __HIP_MEMORY_SCOPE_AGENT);
        if (__ballot(v >= (unsigned)t) == ~0ull) break;
        __builtin_amdgcn_s_sleep(1);
      }
    }
    __syncthreads();   // release waves; drains prestaged chunk 0/1 vmcnt

    const int nch = (t == 0) ? NCX : (NCX + NCH);   // t=0: h==0, skip h chunks
    for (int c = 0; c < nch; ++c) {
      if (c > 0) {
        __syncthreads();                            // chunk c staged, buf c&1^1 free
        if (c + 1 < nch) stage(t, c + 1, (c + 1) & 1);
      }
      const int buf = c & 1;
#pragma unroll
      for (int s = 0; s < 4; ++s) {                 // 4 k-slices of 32
        const int slot = (s * 4 + q) ^ mloc;
        const v8bf av = *(const v8bf*)&Ald[buf][(wv * 16 + mloc) * BK + slot * 8];
#pragma unroll
        for (int g = 0; g < 4; ++g) {
          const v8bf bv = *(const v8bf*)&Bld[buf][(g * 16 + mloc) * BK + slot * 8];
          acc[g] = __builtin_amdgcn_mfma_f32_16x16x32_bf16(av, bv, acc[g], 0, 0, 0);
        }
      }
    }

    // gate update; C/D layout: col = lane&15 (unit), row = q*4 + reg (batch)
    u16* hwrite = p.hbuf + (size_t)((t + 1) & 1) * kB * kH;
#pragma unroll
    for (int r = 0; r < 4; ++r) {
      const float iv = sigm(acc[0][r] + bias[0]);
      const float fv = sigm(acc[1][r] + bias[1]);
      const float gv = tanh_f(acc[2][r] + bias[2]);
      const float ov = sigm(acc[3][r] + bias[3]);
      creg[r] = fv * creg[r] + iv * gv;
      const float hv = ov * tanh_f(creg[r]);
      const int m = mt * 64 + wv * 16 + q * 4 + r;
      hwrite[(size_t)m * kH + uglob] = f2b(hv);
    }

    // arrive: all LDS reads + h stores drained, then wbL2 flush + RMW flag
    // (RMW executes at LLC -> guaranteed cross-XCD visible; validated in r2)
    __syncthreads();
    if (tid == 0) {
      __threadfence();
      __hip_atomic_fetch_add(&gflags[ut], 1u, __ATOMIC_RELAXED,
                             __HIP_MEMORY_SCOPE_AGENT);
    }
    if (t + 1 < kT) {                 // prestage next step's x chunks under barrier wait
      stage(t + 1, 0, 0);
      stage(t + 1, 1, 1);
    }
  }

  // FC + log_softmax: blocks 0..31, 8 batch rows x 32 cols each. h_last in hbuf[0].
  if (blk < 32) {
    const int gg = blk >> 3;   // batch-tile group these 8 rows belong to
    if (wv == 0) {
      while (true) {
        unsigned v = __hip_atomic_load(&p.flags[gg * 64 + lane], __ATOMIC_RELAXED,
                                       __HIP_MEMORY_SCOPE_AGENT);
        if (__ballot(v >= (unsigned)kT) == ~0ull) break;
        __builtin_amdgcn_s_sleep(1);
      }
    }
    __syncthreads();
    u16* sh = &Ald[0][0];   // 16 KB: 8 rows x 1024 bf16
    const char* hbase = (const char*)(p.hbuf + (size_t)blk * 8 * kH);  // buf 0
#pragma unroll
    for (int cc = 0; cc < 4; ++cc) {
      const char* g = hbase + cc * 4096 + wv * 1024 + lane * 16;
      ld16c(g, (char*)sh + cc * 4096 + wv * 1024);
    }
    __syncthreads();
    const int row = tid >> 5;   // 0..7 local row
    const int col = tid & 31;
    const u16* hr = sh + row * kH;
    const float* wr = p.wfc + (size_t)col * kH;
    float s = 0.f;
    for (int k = 0; k < kH; k += 4) {
      const float4 w4 = *(const float4*)(wr + k);
      s += b2f(hr[k]) * w4.x + b2f(hr[k + 1]) * w4.y +
           b2f(hr[k + 2]) * w4.z + b2f(hr[k + 3]) * w4.w;
    }
    float mx = s;
#pragma unroll
    for (int off = 16; off; off >>= 1) mx = fmaxf(mx, __shfl_xor(mx, off, 32));
    const float ex = __expf(s - mx);
    float se = ex;
#pragma unroll
    for (int off = 16; off; off >>= 1) se += __shfl_xor(se, off, 32);
    p.out[(blk * 8 + row) * kO + col] = s - mx - __logf(se);
  }
}

extern "C" void kernel_launch(void* const* d_in, const int* in_sizes, int n_in,
                              void* d_out, int out_size, void* d_ws, size_t ws_size,
                              hipStream_t stream) {
  (void)in_sizes; (void)n_in; (void)out_size; (void)ws_size;
  char* ws = (char*)d_ws;

  // bf16 copies in workspace
  u16* xb = (u16*)(ws + OFF_X);
  u16* wib[4], *whb[4];
  for (int g = 0; g < 4; ++g) {
    wib[g] = (u16*)(ws + OFF_WI + (size_t)g * SZ_WI);
    whb[g] = (u16*)(ws + OFF_WH + (size_t)g * SZ_WH);
  }

  // input dict order: x, (w_ii,w_hi,b_ii,b_hi), (w_if,w_hf,b_if,b_hf),
  //                   (w_io,w_ho,b_io,b_ho), (w_ic,w_hc,b_ic,b_hc), w_fc
  // struct gate order: 0=i, 1=f, 2=g(candidate), 3=o
  const float* xf = (const float*)d_in[0];
  const int gsrc[4] = {1, 5, 13, 9};  // base input index for gates i, f, g, o

  hipMemsetAsync(d_ws, 0, 1024, stream);  // zero barrier flags (ws is 0xAA-poisoned)

  // fp32 -> bf16 conversions
  cvt_kernel<<<2048, 256, 0, stream>>>(xf, xb, kB * kT * kI / 8);
  for (int g = 0; g < 4; ++g) {
    cvt_kernel<<<512, 256, 0, stream>>>((const float*)d_in[gsrc[g]], wib[g], kH * kI / 8);
    cvt_kernel<<<1024, 256, 0, stream>>>((const float*)d_in[gsrc[g] + 1], whb[g], kH * kH / 8);
  }

  LstmParams p;
  p.x = xb;
  for (int g = 0; g < 4; ++g) {
    p.wi[g] = wib[g];
    p.wh[g] = whb[g];
    p.bi[g] = (const float*)d_in[gsrc[g] + 2];
    p.bh[g] = (const float*)d_in[gsrc[g] + 3];
  }
  p.wfc = (const float*)d_in[17];
  p.out = (float*)d_out;
  p.flags = (unsigned*)(ws + OFF_FLG);
  p.hbuf = (u16*)(ws + OFF_H);

  void* args[] = {&p};
  hipLaunchCooperativeKernel((void*)lstm_kernel, dim3(kBlocks), dim3(kThreads),
                             args, 0, stream);
}

// Round 4
// 1633.891 us; speedup vs baseline: 2.9833x; 1.7680x over previous
//
#include <hip/hip_runtime.h>
#include <stdint.h>

#define GAS __attribute__((address_space(1)))
#define LAS __attribute__((address_space(3)))

typedef __bf16 v8bf __attribute__((ext_vector_type(8)));
typedef float v4f __attribute__((ext_vector_type(4)));
typedef unsigned short u16;
typedef unsigned long long u64;

constexpr int kB = 256, kT = 128, kI = 512, kH = 1024, kO = 32;
constexpr int kBlocks = 256, kThreads = 256;
constexpr int BK = 128;
constexpr int NCX = kI / BK;   // 4 x-chunks
constexpr int NC  = (kI + kH) / BK;  // 12 chunks when h included

// workspace layout (bytes)
constexpr size_t OFF_FLG = 0;                                  // flags[4][64] stride-16B
constexpr size_t OFF_H   = 8192;                               // 2 x [B][H] bf16 ping-pong
constexpr size_t OFF_X   = OFF_H + (size_t)2 * kB * kH * 2;    // x as bf16 [B][T][I]
constexpr size_t SZ_X    = (size_t)kB * kT * kI * 2;
constexpr size_t OFF_WI  = OFF_X + SZ_X;                       // 4 x [H][I] bf16
constexpr size_t SZ_WI   = (size_t)kH * kI * 2;
constexpr size_t OFF_WH  = OFF_WI + 4 * SZ_WI;                 // 4 x [H][H] bf16
constexpr size_t SZ_WH   = (size_t)kH * kH * 2;

struct LstmParams {
  const u16* x;         // bf16 (converted) [B][T][I]
  const u16* wi[4];     // bf16 gate order: i, f, g(candidate), o  [H][I]
  const u16* wh[4];     // bf16 [H][H]
  const float* bi[4];   // fp32 [H]
  const float* bh[4];   // fp32 [H]
  const float* wfc;     // fp32 [O][H]
  float* out;           // fp32 [B][O]
  unsigned* flags;      // [4][64] arrival flags, 16B stride
  u16* hbuf;            // 2 x [B][H] bf16 ping-pong (LLC-resident via write-through)
};

static __device__ __forceinline__ float b2f(u16 v) {
  union { float f; uint32_t i; } u; u.i = ((uint32_t)v) << 16; return u.f;
}
static __device__ __forceinline__ u16 f2b(float f) {
  union { float f; uint32_t i; } u; u.f = f;
  return (u16)((u.i + 0x7fffu + ((u.i >> 16) & 1u)) >> 16);
}
static __device__ __forceinline__ float sigm(float x) { return 1.f / (1.f + __expf(-x)); }
static __device__ __forceinline__ float tanh_f(float x) {
  float e = __expf(2.f * x);
  return 1.f - 2.f / (e + 1.f);
}
// plain async global->LDS, 16B/lane (LDS dest = wave-uniform base + lane*16)
static __device__ __forceinline__ void ld16(const void* g, void* l) {
  __builtin_amdgcn_global_load_lds((const GAS uint32_t*)g, (LAS uint32_t*)l, 16, 0, 0);
}
// coherent (sc0|sc1): bypass L1/L2, read LLC — h was written through to LLC
static __device__ __forceinline__ void ld16c(const void* g, void* l) {
  __builtin_amdgcn_global_load_lds((const GAS uint32_t*)g, (LAS uint32_t*)l, 16, 0, 0x11);
}

// fp32 -> bf16 conversion (grid-stride, 8 elems/thread-iter)
__global__ __launch_bounds__(256) void cvt_kernel(const float* __restrict__ s,
                                                  u16* __restrict__ d, int n8) {
  for (int i = blockIdx.x * blockDim.x + threadIdx.x; i < n8;
       i += gridDim.x * blockDim.x) {
    const float4* sp = (const float4*)(s + (size_t)i * 8);
    float4 a = sp[0], b = sp[1];
    uint32_t w0 = f2b(a.x) | ((uint32_t)f2b(a.y) << 16);
    uint32_t w1 = f2b(a.z) | ((uint32_t)f2b(a.w) << 16);
    uint32_t w2 = f2b(b.x) | ((uint32_t)f2b(b.y) << 16);
    uint32_t w3 = f2b(b.z) | ((uint32_t)f2b(b.w) << 16);
    uint4 o = {w0, w1, w2, w3};
    *(uint4*)(d + (size_t)i * 8) = o;
  }
}

__global__ __launch_bounds__(kThreads) void lstm_kernel(LstmParams p) {
  // 4 chunk-buffers (pair-alternating double buffer at group-of-2 granularity)
  __shared__ u16 Abuf[4][64 * BK];   // 64 KB
  __shared__ u16 Bbuf[4][64 * BK];   // 64 KB
  __shared__ u16 Hout[64 * 16];      // 2 KB h repack tile

  const int tid = threadIdx.x;
  const int lane = tid & 63;
  const int wv = tid >> 6;          // wave 0..3: owns batch rows [16wv,16wv+16), stages gate wv
  const int blk = blockIdx.x;
  // XCD-aware swizzle: the 4 blocks sharing a ut land on one XCD (round-robin %8)
  const int mt = (blk >> 3) & 3;            // batch tile 0..3 (64 rows) = barrier group
  const int ut = (blk & 7) * 8 + (blk >> 5);// unit tile 0..63 (16 hidden units)

  const int mloc = lane & 15;       // MFMA row (A) / unit col (B) / out col
  const int q = lane >> 4;          // MFMA quad
  const int uglob = ut * 16 + mloc; // this lane's hidden unit

  unsigned* gflags = p.flags + mt * 256;   // this group's 64 slots (stride 4 u32 = 16B)

  float bias[4];
#pragma unroll
  for (int g = 0; g < 4; ++g)
    bias[g] = p.bi[g][uglob] + p.bh[g][uglob];

  float creg[4] = {0.f, 0.f, 0.f, 0.f};  // cell state, register-resident all 128 steps

  // staging: round rr covers rows [wv*16+rr*4, +4); lane -> (row rl, slot lane&15)
  auto stage = [&](int t_, int c, int bufi) {
    const u16* hread = p.hbuf + (size_t)(t_ & 1) * kB * kH;
#pragma unroll
    for (int rr = 0; rr < 4; ++rr) {
      const int rl = rr * 4 + (lane >> 4);     // 0..15 row within wave's 16
      const int gb = (lane & 15) ^ rl;         // swizzled global blob index
      u16* Adst = &Abuf[bufi][(wv * 16 + rr * 4) * BK];
      u16* Bdst = &Bbuf[bufi][(wv * 16 + rr * 4) * BK];
      const int m = mt * 64 + wv * 16 + rl;    // global batch row
      const int u = ut * 16 + rl;              // global hidden unit (gate wv)
      if (c < NCX) {
        ld16(p.x + ((size_t)m * kT + t_) * kI + c * BK + gb * 8, Adst);
        ld16(p.wi[wv] + (size_t)u * kI + c * BK + gb * 8, Bdst);
      } else {
        ld16c(hread + (size_t)m * kH + (c - NCX) * BK + gb * 8, Adst);
        ld16(p.wh[wv] + (size_t)u * kH + (c - NCX) * BK + gb * 8, Bdst);
      }
    }
  };

  // first-step group 0 prefetch (chunks 0,1 -> bufs 0,1)
  stage(0, 0, 0);
  stage(0, 1, 1);

  for (int t = 0; t < kT; ++t) {
    v4f acc[4];
#pragma unroll
    for (int g = 0; g < 4; ++g) acc[g] = (v4f){0.f, 0.f, 0.f, 0.f};

    if (t > 0 && wv == 0) {
      // group barrier wait: 64 lanes read 64 padded flags (relaxed, LLC)
      while (true) {
        unsigned v = __hip_atomic_load(&gflags[lane * 4], __ATOMIC_RELAXED,
                                       __HIP_MEMORY_SCOPE_AGENT);
        if (__ballot(v >= (unsigned)t) == ~0ull) break;
        __builtin_amdgcn_s_sleep(1);
      }
    }

    const int ngrp = (t == 0) ? 2 : 6;   // t=0: h==0, x chunks only
    for (int g = 0; g < ngrp; ++g) {
      __syncthreads();   // group g staged; group g-1's ds_reads drained (lgkmcnt)
      if (g + 1 < ngrp) {                // stage group g+1 into the pair freed by g-1
        stage(t, 2 * (g + 1), (2 * (g + 1)) & 3);
        stage(t, 2 * (g + 1) + 1, (2 * (g + 1) + 1) & 3);
      }
#pragma unroll
      for (int cc2 = 0; cc2 < 2; ++cc2) {
        const int buf = (2 * g + cc2) & 3;
#pragma unroll
        for (int s = 0; s < 4; ++s) {               // 4 k-slices of 32
          const int slot = (s * 4 + q) ^ mloc;
          const v8bf av = *(const v8bf*)&Abuf[buf][(wv * 16 + mloc) * BK + slot * 8];
#pragma unroll
          for (int gg = 0; gg < 4; ++gg) {
            const v8bf bv = *(const v8bf*)&Bbuf[buf][(gg * 16 + mloc) * BK + slot * 8];
            acc[gg] = __builtin_amdgcn_mfma_f32_16x16x32_bf16(av, bv, acc[gg], 0, 0, 0);
          }
        }
      }
    }

    // gate update; C/D layout: col = lane&15 (unit), row = q*4 + reg (batch)
    // repack h through LDS so the global write-through is coalesced 8B stores
#pragma unroll
    for (int r = 0; r < 4; ++r) {
      const float iv = sigm(acc[0][r] + bias[0]);
      const float fv = sigm(acc[1][r] + bias[1]);
      const float gv = tanh_f(acc[2][r] + bias[2]);
      const float ov = sigm(acc[3][r] + bias[3]);
      creg[r] = fv * creg[r] + iv * gv;
      const float hv = ov * tanh_f(creg[r]);
      Hout[(wv * 16 + q * 4 + r) * 16 + mloc] = f2b(hv);
    }
    __syncthreads();   // Hout complete

    // write-through h to LLC (sc0|sc1 via relaxed agent atomic store — no wbl2!)
    u16* hwrite = p.hbuf + (size_t)((t + 1) & 1) * kB * kH;
    {
      const int rr = tid >> 2;     // local row 0..63
      const int c4 = tid & 3;      // 4-unit group
      const u64 v = *(const u64*)&Hout[rr * 16 + c4 * 4];
      u64* dst = (u64*)(hwrite + (size_t)(mt * 64 + rr) * kH + ut * 16 + c4 * 4);
      __hip_atomic_store(dst, v, __ATOMIC_RELAXED, __HIP_MEMORY_SCOPE_AGENT);
    }
    __syncthreads();   // per-wave vmcnt(0) at barrier => all h stores acked at LLC

    if (tid == 0) {
      __hip_atomic_fetch_add(&gflags[ut * 4], 1u, __ATOMIC_RELAXED,
                             __HIP_MEMORY_SCOPE_AGENT);
    }
    if (t + 1 < kT) {                 // prestage next step's group 0 under barrier wait
      stage(t + 1, 0, 0);
      stage(t + 1, 1, 1);
    }
  }

  // FC + log_softmax: blocks 0..31, 8 batch rows x 32 cols each. h_last in hbuf[0].
  if (blk < 32) {
    const int gg = blk >> 3;   // batch-tile group these 8 rows belong to
    if (wv == 0) {
      while (true) {
        unsigned v = __hip_atomic_load(&p.flags[gg * 256 + lane * 4], __ATOMIC_RELAXED,
                                       __HIP_MEMORY_SCOPE_AGENT);
        if (__ballot(v >= (unsigned)kT) == ~0ull) break;
        __builtin_amdgcn_s_sleep(1);
      }
    }
    __syncthreads();
    u16* sh = &Abuf[0][0];   // 16 KB: 8 rows x 1024 bf16
    const char* hbase = (const char*)(p.hbuf + (size_t)blk * 8 * kH);  // buf 0
#pragma unroll
    for (int cc = 0; cc < 4; ++cc) {
      const char* g = hbase + cc * 4096 + wv * 1024 + lane * 16;
      ld16c(g, (char*)sh + cc * 4096 + wv * 1024);
    }
    __syncthreads();
    const int row = tid >> 5;   // 0..7 local row
    const int col = tid & 31;
    const u16* hr = sh + row * kH;
    const float* wr = p.wfc + (size_t)col * kH;
    float s = 0.f;
    for (int k = 0; k < kH; k += 4) {
      const float4 w4 = *(const float4*)(wr + k);
      s += b2f(hr[k]) * w4.x + b2f(hr[k + 1]) * w4.y +
           b2f(hr[k + 2]) * w4.z + b2f(hr[k + 3]) * w4.w;
    }
    float mx = s;
#pragma unroll
    for (int off = 16; off; off >>= 1) mx = fmaxf(mx, __shfl_xor(mx, off, 32));
    const float ex = __expf(s - mx);
    float se = ex;
#pragma unroll
    for (int off = 16; off; off >>= 1) se += __shfl_xor(se, off, 32);
    p.out[(blk * 8 + row) * kO + col] = s - mx - __logf(se);
  }
}

extern "C" void kernel_launch(void* const* d_in, const int* in_sizes, int n_in,
                              void* d_out, int out_size, void* d_ws, size_t ws_size,
                              hipStream_t stream) {
  (void)in_sizes; (void)n_in; (void)out_size; (void)ws_size;
  char* ws = (char*)d_ws;

  // bf16 copies in workspace
  u16* xb = (u16*)(ws + OFF_X);
  u16* wib[4], *whb[4];
  for (int g = 0; g < 4; ++g) {
    wib[g] = (u16*)(ws + OFF_WI + (size_t)g * SZ_WI);
    whb[g] = (u16*)(ws + OFF_WH + (size_t)g * SZ_WH);
  }

  // input dict order: x, (w_ii,w_hi,b_ii,b_hi), (w_if,w_hf,b_if,b_hf),
  //                   (w_io,w_ho,b_io,b_ho), (w_ic,w_hc,b_ic,b_hc), w_fc
  // struct gate order: 0=i, 1=f, 2=g(candidate), 3=o
  const float* xf = (const float*)d_in[0];
  const int gsrc[4] = {1, 5, 13, 9};  // base input index for gates i, f, g, o

  hipMemsetAsync(d_ws, 0, 8192, stream);  // zero barrier flags (ws is 0xAA-poisoned)

  // fp32 -> bf16 conversions
  cvt_kernel<<<2048, 256, 0, stream>>>(xf, xb, kB * kT * kI / 8);
  for (int g = 0; g < 4; ++g) {
    cvt_kernel<<<512, 256, 0, stream>>>((const float*)d_in[gsrc[g]], wib[g], kH * kI / 8);
    cvt_kernel<<<1024, 256, 0, stream>>>((const float*)d_in[gsrc[g] + 1], whb[g], kH * kH / 8);
  }

  LstmParams p;
  p.x = xb;
  for (int g = 0; g < 4; ++g) {
    p.wi[g] = wib[g];
    p.wh[g] = whb[g];
    p.bi[g] = (const float*)d_in[gsrc[g] + 2];
    p.bh[g] = (const float*)d_in[gsrc[g] + 3];
  }
  p.wfc = (const float*)d_in[17];
  p.out = (float*)d_out;
  p.flags = (unsigned*)(ws + OFF_FLG);
  p.hbuf = (u16*)(ws + OFF_H);

  void* args[] = {&p};
  hipLaunchCooperativeKernel((void*)lstm_kernel, dim3(kBlocks), dim3(kThreads),
                             args, 0, stream);
}